// Round 6
// baseline (847.318 us; speedup 1.0000x reference)
//
#include <hip/hip_runtime.h>
#include <hip/hip_bf16.h>
#include <stdint.h>

#define T_TOK 2048
#define H_DIM 1024
#define I_DIM 4096
#define E_NUM 8

#define GBM 256          // gateup/down M-tile (512 threads, 4M x 2N waves)
#define BN 64
#define KS 2             // split-K for down

typedef unsigned short u16;
typedef __bf16 bf16_t;
typedef bf16_t bf16x8 __attribute__((ext_vector_type(8)));
typedef float f32x4 __attribute__((ext_vector_type(4)));

__device__ __forceinline__ u16 f2bf(float f) {
  union { float f; unsigned u; } a; a.f = f;
  unsigned r = a.u + 0x7FFFu + ((a.u >> 16) & 1u);  // RNE
  return (u16)(r >> 16);
}

// cheap GELU: tanh-approx via sigmoid, max abs err ~3e-4 (4x headroom vs threshold)
__device__ __forceinline__ float gelu_fast(float g) {
  float y = g * (0.7978845608f + 0.0356774081f * g * g);
  return g / (1.0f + __expf(-2.0f * y));
}

// 8 fp32 -> bf16x8 via native casts (compiler emits v_cvt_pk_bf16_f32 pairs)
__device__ __forceinline__ bf16x8 cvt8(float4 a, float4 b) {
  bf16x8 r;
  r[0] = (bf16_t)a.x; r[1] = (bf16_t)a.y; r[2] = (bf16_t)a.z; r[3] = (bf16_t)a.w;
  r[4] = (bf16_t)b.x; r[5] = (bf16_t)b.y; r[6] = (bf16_t)b.z; r[7] = (bf16_t)b.w;
  return r;
}

// ---------------- prep: zero out/counts, convert x -> bf16 ----------------
__global__ __launch_bounds__(256) void k_prep(const float* __restrict__ x,
                                              float* __restrict__ out,
                                              u16* __restrict__ xb,
                                              int* __restrict__ counts) {
  int i = blockIdx.x * 256 + threadIdx.x;
  if (i < E_NUM) counts[i] = 0;
  float4 v = reinterpret_cast<const float4*>(x)[i];
  ushort4 b;
  b.x = f2bf(v.x); b.y = f2bf(v.y); b.z = f2bf(v.z); b.w = f2bf(v.w);
  reinterpret_cast<ushort4*>(xb)[i] = b;
  reinterpret_cast<float4*>(out)[i] = make_float4(0.f, 0.f, 0.f, 0.f);
}

// ---------------- router: fp32 logits, softcap, softmax, top-2 ----------------
__global__ __launch_bounds__(256) void k_router(const float* __restrict__ x,
                                                const float* __restrict__ gw,
                                                int* __restrict__ counts,
                                                int* __restrict__ ids,
                                                float* __restrict__ wts) {
  int gtid = blockIdx.x * 256 + threadIdx.x;
  int t = gtid >> 6;
  int lane = threadIdx.x & 63;
  if (t >= T_TOK) return;
  const float* xr = x + (size_t)t * H_DIM;
  float4 xv[4];
#pragma unroll
  for (int j = 0; j < 4; ++j) xv[j] = reinterpret_cast<const float4*>(xr)[lane + 64 * j];
  float logit[E_NUM];
#pragma unroll
  for (int e = 0; e < E_NUM; ++e) {
    const float4* gr = reinterpret_cast<const float4*>(gw + (size_t)e * H_DIM);
    float s = 0.f;
#pragma unroll
    for (int j = 0; j < 4; ++j) {
      float4 g = gr[lane + 64 * j];
      s += xv[j].x * g.x + xv[j].y * g.y + xv[j].z * g.z + xv[j].w * g.w;
    }
#pragma unroll
    for (int off = 32; off; off >>= 1) s += __shfl_xor(s, off);
    logit[e] = s;
  }
  if (lane == 0) {
    float cap[E_NUM], mx = -1e30f;
#pragma unroll
    for (int e = 0; e < E_NUM; ++e) {
      cap[e] = 30.f * tanhf(logit[e] * (1.f / 30.f));
      mx = fmaxf(mx, cap[e]);
    }
    float p[E_NUM], sum = 0.f;
#pragma unroll
    for (int e = 0; e < E_NUM; ++e) { p[e] = expf(cap[e] - mx); sum += p[e]; }
    int i1 = 0; float p1 = p[0];
#pragma unroll
    for (int e = 1; e < E_NUM; ++e) if (p[e] > p1) { p1 = p[e]; i1 = e; }
    int i2 = -1; float p2 = -1.f;
#pragma unroll
    for (int e = 0; e < E_NUM; ++e) if (e != i1 && p[e] > p2) { p2 = p[e]; i2 = e; }
    float inv = 1.f / sum;
    int s1 = atomicAdd(&counts[i1], 1);
    ids[i1 * T_TOK + s1] = t; wts[i1 * T_TOK + s1] = p1 * inv;
    int s2 = atomicAdd(&counts[i2], 1);
    ids[i2 * T_TOK + s2] = t; wts[i2 * T_TOK + s2] = p2 * inv;
  }
}

__global__ void k_offs(const int* __restrict__ counts, int* __restrict__ offs) {
  if (threadIdx.x == 0) {
    int a = 0;
    for (int e = 0; e < E_NUM; ++e) { offs[e] = a; a += counts[e]; }
  }
}

// ============ gate/up GEMM: frag-direct, NO LDS, NO barriers ============
// 512 thr = 8 waves (4M x 2N), block tile 256x64, K step 32, 2-set reg pipeline.
__global__ __launch_bounds__(512, 2) void k_gateup5(
    const u16* __restrict__ xb, const float* __restrict__ w1g, const float* __restrict__ w1u,
    const int* __restrict__ counts, const int* __restrict__ offs, const int* __restrict__ ids,
    u16* __restrict__ h) {
  const int e = blockIdx.z, mt = blockIdx.y, nt = blockIdx.x;
  const int cnt = counts[e];
  if (mt * GBM >= cnt) return;
  const int tid = threadIdx.x, lane = tid & 63, wid = tid >> 6;
  const int wr = (wid >> 1) * 64, wc = (wid & 1) * 32;
  const int lr = lane & 15, lk = lane >> 4;
  const int i0 = nt * BN;

  // A fragment row pointers (token gather): lane covers row = wr+mi*16+lr, k = lk*8..+8
  const u16* aptr[4];
#pragma unroll
  for (int mi = 0; mi < 4; ++mi) {
    int rg = mt * GBM + wr + mi * 16 + lr;
    if (rg >= cnt) rg = cnt - 1;
    aptr[mi] = xb + (size_t)ids[e * T_TOK + rg] * H_DIM + lk * 8;
  }
  // B fragment row pointers (fp32 weights, streamed): row = i0+wc+ni*16+lr
  const float *gptr[2], *uptr[2];
#pragma unroll
  for (int ni = 0; ni < 2; ++ni) {
    size_t row = (size_t)e * I_DIM + i0 + wc + ni * 16 + lr;
    gptr[ni] = w1g + row * H_DIM + lk * 8;
    uptr[ni] = w1u + row * H_DIM + lk * 8;
  }

  f32x4 accg[4][2], accu[4][2];
#pragma unroll
  for (int mi = 0; mi < 4; ++mi)
#pragma unroll
    for (int ni = 0; ni < 2; ++ni) { accg[mi][ni] = (f32x4)0.f; accu[mi][ni] = (f32x4)0.f; }

  uint4 a0[4], a1[4];
  float4 g0[2][2], g1[2][2], u0[2][2], u1[2][2];

#define LOAD_SET(A, G, U, kt) do {                                              \
    const int ko = (kt) * 32;                                                   \
    _Pragma("unroll") for (int mi = 0; mi < 4; ++mi)                            \
      A[mi] = *reinterpret_cast<const uint4*>(aptr[mi] + ko);                   \
    _Pragma("unroll") for (int ni = 0; ni < 2; ++ni) {                          \
      G[ni][0] = *reinterpret_cast<const float4*>(gptr[ni] + ko);               \
      G[ni][1] = *reinterpret_cast<const float4*>(gptr[ni] + ko + 4);           \
      U[ni][0] = *reinterpret_cast<const float4*>(uptr[ni] + ko);               \
      U[ni][1] = *reinterpret_cast<const float4*>(uptr[ni] + ko + 4);           \
    } } while (0)

#define MFMA_SET(A, G, U) do {                                                  \
    _Pragma("unroll") for (int ni = 0; ni < 2; ++ni) {                          \
      bf16x8 bg = cvt8(G[ni][0], G[ni][1]);                                     \
      bf16x8 bu = cvt8(U[ni][0], U[ni][1]);                                     \
      _Pragma("unroll") for (int mi = 0; mi < 4; ++mi) {                        \
        bf16x8 a = *reinterpret_cast<const bf16x8*>(&A[mi]);                    \
        accg[mi][ni] = __builtin_amdgcn_mfma_f32_16x16x32_bf16(a, bg, accg[mi][ni], 0, 0, 0); \
        accu[mi][ni] = __builtin_amdgcn_mfma_f32_16x16x32_bf16(a, bu, accu[mi][ni], 0, 0, 0); \
      } } } while (0)

  const int NT = H_DIM / 32;   // 32 K-steps
  LOAD_SET(a0, g0, u0, 0);
  for (int kt = 0; kt < NT; kt += 2) {
    LOAD_SET(a1, g1, u1, kt + 1);          // kt+1 <= NT-1 always (NT even)
    MFMA_SET(a0, g0, u0);
    if (kt + 2 < NT) LOAD_SET(a0, g0, u0, kt + 2);
    MFMA_SET(a1, g1, u1);
  }
#undef LOAD_SET
#undef MFMA_SET

  const int hbase = offs[e];
#pragma unroll
  for (int mi = 0; mi < 4; ++mi)
#pragma unroll
    for (int rr = 0; rr < 4; ++rr) {
      int grow = mt * GBM + wr + mi * 16 + lk * 4 + rr;   // C/D: row=(lane>>4)*4+reg
      if (grow < cnt) {
        size_t hrow = (size_t)(hbase + grow) * I_DIM;
#pragma unroll
        for (int ni = 0; ni < 2; ++ni) {
          int col = i0 + wc + ni * 16 + lr;               // C/D: col=lane&15
          h[hrow + col] = f2bf(gelu_fast(accg[mi][ni][rr]) * accu[mi][ni][rr]);
        }
      }
    }
}

// ============ down GEMM: frag-direct, NO LDS, split-K + weighted scatter-add ============
__global__ __launch_bounds__(512, 2) void k_down5(
    const u16* __restrict__ h, const float* __restrict__ w2,
    const int* __restrict__ counts, const int* __restrict__ offs, const int* __restrict__ ids,
    const float* __restrict__ wts, float* __restrict__ out) {
  const int e = blockIdx.z, mt = blockIdx.y;
  const int nt = blockIdx.x & 15, ks = blockIdx.x >> 4;
  const int cnt = counts[e];
  if (mt * GBM >= cnt) return;
  const int tid = threadIdx.x, lane = tid & 63, wid = tid >> 6;
  const int wr = (wid >> 1) * 64, wc = (wid & 1) * 32;
  const int lr = lane & 15, lk = lane >> 4;
  const int n0 = nt * BN;
  const int hbase = offs[e];
  const int kbase = ks * (I_DIM / KS);     // split-K element base

  const u16* aptr[4];
#pragma unroll
  for (int mi = 0; mi < 4; ++mi) {
    int rg = mt * GBM + wr + mi * 16 + lr;
    if (rg >= cnt) rg = cnt - 1;
    aptr[mi] = h + (size_t)(hbase + rg) * I_DIM + kbase + lk * 8;
  }
  const float* bptr[2];
#pragma unroll
  for (int ni = 0; ni < 2; ++ni)
    bptr[ni] = w2 + (size_t)(e * H_DIM + n0 + wc + ni * 16 + lr) * I_DIM + kbase + lk * 8;

  f32x4 acc[4][2];
#pragma unroll
  for (int mi = 0; mi < 4; ++mi)
#pragma unroll
    for (int ni = 0; ni < 2; ++ni) acc[mi][ni] = (f32x4)0.f;

  uint4 a0[4], a1[4];
  float4 b0[2][2], b1[2][2];

#define LOAD_SET(A, B, kt) do {                                                 \
    const int ko = (kt) * 32;                                                   \
    _Pragma("unroll") for (int mi = 0; mi < 4; ++mi)                            \
      A[mi] = *reinterpret_cast<const uint4*>(aptr[mi] + ko);                   \
    _Pragma("unroll") for (int ni = 0; ni < 2; ++ni) {                          \
      B[ni][0] = *reinterpret_cast<const float4*>(bptr[ni] + ko);               \
      B[ni][1] = *reinterpret_cast<const float4*>(bptr[ni] + ko + 4);           \
    } } while (0)

#define MFMA_SET(A, B) do {                                                     \
    _Pragma("unroll") for (int ni = 0; ni < 2; ++ni) {                          \
      bf16x8 bb = cvt8(B[ni][0], B[ni][1]);                                     \
      _Pragma("unroll") for (int mi = 0; mi < 4; ++mi) {                        \
        bf16x8 a = *reinterpret_cast<const bf16x8*>(&A[mi]);                    \
        acc[mi][ni] = __builtin_amdgcn_mfma_f32_16x16x32_bf16(a, bb, acc[mi][ni], 0, 0, 0); \
      } } } while (0)

  const int NT = (I_DIM / KS) / 32;   // 64 K-steps
  LOAD_SET(a0, b0, 0);
  for (int kt = 0; kt < NT; kt += 2) {
    LOAD_SET(a1, b1, kt + 1);
    MFMA_SET(a0, b0);
    if (kt + 2 < NT) LOAD_SET(a0, b0, kt + 2);
    MFMA_SET(a1, b1);
  }
#undef LOAD_SET
#undef MFMA_SET

#pragma unroll
  for (int mi = 0; mi < 4; ++mi)
#pragma unroll
    for (int rr = 0; rr < 4; ++rr) {
      int grow = mt * GBM + wr + mi * 16 + lk * 4 + rr;
      if (grow < cnt) {
        int tok = ids[e * T_TOK + grow];
        float w = wts[e * T_TOK + grow];
#pragma unroll
        for (int ni = 0; ni < 2; ++ni) {
          int col = n0 + wc + ni * 16 + lr;
          atomicAdd(&out[(size_t)tok * H_DIM + col], w * acc[mi][ni][rr]);
        }
      }
    }
}

extern "C" void kernel_launch(void* const* d_in, const int* in_sizes, int n_in,
                              void* d_out, int out_size, void* d_ws, size_t ws_size,
                              hipStream_t stream) {
  const float* x   = (const float*)d_in[0];
  const float* gw  = (const float*)d_in[1];
  const float* w1g = (const float*)d_in[2];
  const float* w1u = (const float*)d_in[3];
  const float* w2  = (const float*)d_in[4];
  float* out = (float*)d_out;
  char* ws = (char*)d_ws;

  const size_t MB = 1u << 20;
  const size_t OFF_XB  = 0;                    // 4 MB
  const size_t OFF_H   = 4 * MB;               // 32 MB
  const size_t OFF_IDS = OFF_H + 32 * MB;
  const size_t OFF_WTS = OFF_IDS + (64u << 10);
  const size_t OFF_CNT = OFF_WTS + (64u << 10);

  u16* xb     = (u16*)(ws + OFF_XB);
  u16* h      = (u16*)(ws + OFF_H);
  int* ids    = (int*)(ws + OFF_IDS);
  float* wts  = (float*)(ws + OFF_WTS);
  int* counts = (int*)(ws + OFF_CNT);
  int* offs   = counts + 8;

  k_prep<<<2048, 256, 0, stream>>>(x, out, xb, counts);
  k_router<<<512, 256, 0, stream>>>(x, gw, counts, ids, wts);
  k_offs<<<1, 64, 0, stream>>>(counts, offs);
  k_gateup5<<<dim3(I_DIM / BN, T_TOK / GBM, E_NUM), 512, 0, stream>>>(
      xb, w1g, w1u, counts, offs, ids, h);
  k_down5<<<dim3((H_DIM / BN) * KS, T_TOK / GBM, E_NUM), 512, 0, stream>>>(
      h, w2, counts, offs, ids, wts, out);
}

// Round 7
// 776.467 us; speedup vs baseline: 1.0912x; 1.0912x over previous
//
#include <hip/hip_runtime.h>
#include <hip/hip_bf16.h>
#include <stdint.h>

#define T_TOK 2048
#define H_DIM 1024
#define I_DIM 4096
#define E_NUM 8

#define GBM 256          // gateup M-tile (512 threads, 8 waves 4Mx2N)
#define BM 128           // down M-tile (256 threads, 4 waves 2Mx2N)
#define BN 64
#define BK 64
#define KS 2             // split-K for down

typedef unsigned short u16;
typedef __bf16 bf16_t;
typedef bf16_t bf16x8 __attribute__((ext_vector_type(8)));
typedef float f32x4 __attribute__((ext_vector_type(4)));

#define WAITV(N) asm volatile("s_waitcnt vmcnt(" #N ")" ::: "memory")
#define WAITL()  asm volatile("s_waitcnt lgkmcnt(0)" ::: "memory")
#define BARRIER() asm volatile("s_barrier" ::: "memory")
#define SCHEDB() __builtin_amdgcn_sched_barrier(0)

__device__ __forceinline__ u16 f2bf(float f) {
  union { float f; unsigned u; } a; a.f = f;
  unsigned r = a.u + 0x7FFFu + ((a.u >> 16) & 1u);  // RNE
  return (u16)(r >> 16);
}

__device__ __forceinline__ void gload_lds16(const void* g, void* l) {
  __builtin_amdgcn_global_load_lds(
      (const __attribute__((address_space(1))) void*)g,
      (__attribute__((address_space(3))) void*)l, 16, 0, 0);
}

// cheap GELU: tanh-approx via sigmoid, max abs err ~3e-4 (4x headroom vs threshold)
__device__ __forceinline__ float gelu_fast(float g) {
  float y = g * (0.7978845608f + 0.0356774081f * g * g);
  return g / (1.0f + __expf(-2.0f * y));
}

__device__ __forceinline__ uint4 pack8(float4 f0, float4 f1) {
  union { uint4 u; u16 s[8]; } p;
  p.s[0] = f2bf(f0.x); p.s[1] = f2bf(f0.y); p.s[2] = f2bf(f0.z); p.s[3] = f2bf(f0.w);
  p.s[4] = f2bf(f1.x); p.s[5] = f2bf(f1.y); p.s[6] = f2bf(f1.z); p.s[7] = f2bf(f1.w);
  return p.u;
}

// ---------------- prep: zero out/counts, convert x -> bf16 ----------------
__global__ __launch_bounds__(256) void k_prep(const float* __restrict__ x,
                                              float* __restrict__ out,
                                              u16* __restrict__ xb,
                                              int* __restrict__ counts) {
  int i = blockIdx.x * 256 + threadIdx.x;
  if (i < E_NUM) counts[i] = 0;
  float4 v = reinterpret_cast<const float4*>(x)[i];
  ushort4 b;
  b.x = f2bf(v.x); b.y = f2bf(v.y); b.z = f2bf(v.z); b.w = f2bf(v.w);
  reinterpret_cast<ushort4*>(xb)[i] = b;
  reinterpret_cast<float4*>(out)[i] = make_float4(0.f, 0.f, 0.f, 0.f);
}

// ---------------- router: fp32 logits, softcap, softmax, top-2 ----------------
__global__ __launch_bounds__(256) void k_router(const float* __restrict__ x,
                                                const float* __restrict__ gw,
                                                int* __restrict__ counts,
                                                int* __restrict__ ids,
                                                float* __restrict__ wts) {
  int gtid = blockIdx.x * 256 + threadIdx.x;
  int t = gtid >> 6;
  int lane = threadIdx.x & 63;
  if (t >= T_TOK) return;
  const float* xr = x + (size_t)t * H_DIM;
  float4 xv[4];
#pragma unroll
  for (int j = 0; j < 4; ++j) xv[j] = reinterpret_cast<const float4*>(xr)[lane + 64 * j];
  float logit[E_NUM];
#pragma unroll
  for (int e = 0; e < E_NUM; ++e) {
    const float4* gr = reinterpret_cast<const float4*>(gw + (size_t)e * H_DIM);
    float s = 0.f;
#pragma unroll
    for (int j = 0; j < 4; ++j) {
      float4 g = gr[lane + 64 * j];
      s += xv[j].x * g.x + xv[j].y * g.y + xv[j].z * g.z + xv[j].w * g.w;
    }
#pragma unroll
    for (int off = 32; off; off >>= 1) s += __shfl_xor(s, off);
    logit[e] = s;
  }
  if (lane == 0) {
    float cap[E_NUM], mx = -1e30f;
#pragma unroll
    for (int e = 0; e < E_NUM; ++e) {
      cap[e] = 30.f * tanhf(logit[e] * (1.f / 30.f));
      mx = fmaxf(mx, cap[e]);
    }
    float p[E_NUM], sum = 0.f;
#pragma unroll
    for (int e = 0; e < E_NUM; ++e) { p[e] = expf(cap[e] - mx); sum += p[e]; }
    int i1 = 0; float p1 = p[0];
#pragma unroll
    for (int e = 1; e < E_NUM; ++e) if (p[e] > p1) { p1 = p[e]; i1 = e; }
    int i2 = -1; float p2 = -1.f;
#pragma unroll
    for (int e = 0; e < E_NUM; ++e) if (e != i1 && p[e] > p2) { p2 = p[e]; i2 = e; }
    float inv = 1.f / sum;
    int s1 = atomicAdd(&counts[i1], 1);
    ids[i1 * T_TOK + s1] = t; wts[i1 * T_TOK + s1] = p1 * inv;
    int s2 = atomicAdd(&counts[i2], 1);
    ids[i2 * T_TOK + s2] = t; wts[i2 * T_TOK + s2] = p2 * inv;
  }
}

__global__ void k_offs(const int* __restrict__ counts, int* __restrict__ offs) {
  if (threadIdx.x == 0) {
    int a = 0;
    for (int e = 0; e < E_NUM; ++e) { offs[e] = a; a += counts[e]; }
  }
}

// ===================== gate/up GEMM: counted-vmcnt pipeline =====================
// A (tokens, bf16): gload_lds into static dbuf As0/As1.
// B (w1 fp32): reg-load kt+1 early -> compute kt -> cvt+ds_write kt+1 late (T14).
// Raw s_barrier + explicit vmcnt(8)/vmcnt(4); never vmcnt(0) in the loop.
__global__ __launch_bounds__(512) void k_gateup6(
    const u16* __restrict__ xb, const float* __restrict__ w1g, const float* __restrict__ w1u,
    const float* __restrict__ w2, u16* __restrict__ w2b,
    const int* __restrict__ counts, const int* __restrict__ offs, const int* __restrict__ ids,
    u16* __restrict__ h) {
  if (blockIdx.z == E_NUM) {
    // fused w2 fp32->bf16 conversion, hidden under gateup compute
    int bid = blockIdx.y * gridDim.x + blockIdx.x;       // 0..511
    const int N4 = E_NUM * H_DIM * I_DIM / 4;
    for (int i = bid * 512 + threadIdx.x; i < N4; i += 512 * 512) {
      float4 v = reinterpret_cast<const float4*>(w2)[i];
      ushort4 b;
      b.x = f2bf(v.x); b.y = f2bf(v.y); b.z = f2bf(v.z); b.w = f2bf(v.w);
      reinterpret_cast<ushort4*>(w2b)[i] = b;
    }
    return;
  }
  const int e = blockIdx.z, mt = blockIdx.x, nt = blockIdx.y;  // mt fastest: B-tile L2 reuse
  const int cnt = counts[e];
  if (mt * GBM >= cnt) return;
  // static double-buffers (separate arrays -> compiler derives precise vmcnt)
  __shared__ u16 As0[GBM * BK], As1[GBM * BK];   // 32 KB each
  __shared__ u16 Bg0[BN * BK],  Bg1[BN * BK];    // 8 KB each
  __shared__ u16 Bu0[BN * BK],  Bu1[BN * BK];    // 8 KB each
  const int tid = threadIdx.x, lane = tid & 63, wid = tid >> 6;
  const int wr = (wid >> 1) * 64, wc = (wid & 1) * 32;
  const int lr = lane & 15, lk = lane >> 4;
  const int i0 = nt * BN;
  const int lrow = lane >> 3;
  const int lgs = (lane & 7) ^ (lrow & 7);   // pre-swizzled A source granule (rule #21)
  const int sw = lr & 7;                     // read-side XOR key

  const u16* asrc[4];
#pragma unroll
  for (int i = 0; i < 4; ++i) {
    int rg = mt * GBM + wid * 32 + i * 8 + lrow;
    if (rg >= cnt) rg = cnt - 1;
    asrc[i] = xb + (size_t)ids[e * T_TOK + rg] * H_DIM + lgs * 8;
  }
  const int awofs = wid * 32 * BK;           // wave-uniform LDS offset

  const int br = tid >> 3, bc = tid & 7;     // B: 64 rows x 8 granules
  const float* gsrc = w1g + (size_t)(e * I_DIM + i0 + br) * H_DIM + bc * 8;
  const float* usrc = w1u + (size_t)(e * I_DIM + i0 + br) * H_DIM + bc * 8;
  const int wgo = br * BK + ((bc ^ (br & 7)) << 3);
  float4 RG0, RG1, RU0, RU1;

  f32x4 accg[4][2], accu[4][2];
#pragma unroll
  for (int mi = 0; mi < 4; ++mi)
#pragma unroll
    for (int ni = 0; ni < 2; ++ni) { accg[mi][ni] = (f32x4)0.f; accu[mi][ni] = (f32x4)0.f; }

#define GU_LOADB(ko) do {                                                   \
    RG0 = *reinterpret_cast<const float4*>(gsrc + (ko));                    \
    RG1 = *reinterpret_cast<const float4*>(gsrc + (ko) + 4);                \
    RU0 = *reinterpret_cast<const float4*>(usrc + (ko));                    \
    RU1 = *reinterpret_cast<const float4*>(usrc + (ko) + 4);                \
  } while (0)
#define GU_STAGE_A(DST, ko) do {                                            \
    _Pragma("unroll") for (int i = 0; i < 4; ++i)                           \
      gload_lds16(asrc[i] + (ko), (u16*)(DST) + awofs + i * 8 * BK);        \
  } while (0)
#define GU_WRITEB(BG, BU) do {                                              \
    *reinterpret_cast<uint4*>((u16*)(BG) + wgo) = pack8(RG0, RG1);          \
    *reinterpret_cast<uint4*>((u16*)(BU) + wgo) = pack8(RU0, RU1);          \
  } while (0)
#define GU_COMPUTE(AS, BG, BU) do {                                         \
    _Pragma("unroll") for (int kk = 0; kk < 2; ++kk) {                      \
      const int colg = kk * 4 + lk;                                         \
      const int gsw = (colg ^ sw) << 3;                                     \
      bf16x8 a[4], bg[2], bu[2];                                            \
      _Pragma("unroll") for (int mi = 0; mi < 4; ++mi)                      \
        a[mi] = *reinterpret_cast<const bf16x8*>((u16*)(AS) + (wr + mi * 16 + lr) * BK + gsw); \
      _Pragma("unroll") for (int ni = 0; ni < 2; ++ni) {                    \
        bg[ni] = *reinterpret_cast<const bf16x8*>((u16*)(BG) + (wc + ni * 16 + lr) * BK + gsw); \
        bu[ni] = *reinterpret_cast<const bf16x8*>((u16*)(BU) + (wc + ni * 16 + lr) * BK + gsw); \
      }                                                                     \
      __builtin_amdgcn_s_setprio(1);                                        \
      _Pragma("unroll") for (int mi = 0; mi < 4; ++mi)                      \
        _Pragma("unroll") for (int ni = 0; ni < 2; ++ni) {                  \
          accg[mi][ni] = __builtin_amdgcn_mfma_f32_16x16x32_bf16(a[mi], bg[ni], accg[mi][ni], 0, 0, 0); \
          accu[mi][ni] = __builtin_amdgcn_mfma_f32_16x16x32_bf16(a[mi], bu[ni], accu[mi][ni], 0, 0, 0); \
        }                                                                   \
      __builtin_amdgcn_s_setprio(0);                                        \
    }                                                                       \
  } while (0)
// ledger: enter iter with A(kt)x4 outstanding. issue B(kt+1)x4 then A(kt+1)x4 -> 12.
// vmcnt(8) drains A(kt). post-compute vmcnt(4) drains B(kt+1), keeps A(kt+1).
#define GU_ITER(ASC, BGC, BUC, ASN, BGN, BUN, kt) do {                      \
    GU_LOADB(((kt) + 1) * BK);                                              \
    SCHEDB();                                                               \
    GU_STAGE_A(ASN, ((kt) + 1) * BK);                                       \
    SCHEDB();                                                               \
    WAITV(8);                                                               \
    BARRIER();                                                              \
    GU_COMPUTE(ASC, BGC, BUC);                                              \
    WAITV(4);                                                               \
    GU_WRITEB(BGN, BUN);                                                    \
    WAITL();                                                                \
    BARRIER();                                                              \
  } while (0)

  // prologue: B(0) loads first (oldest), A(0) stage; drain B(0) only, write it.
  GU_LOADB(0);
  SCHEDB();
  GU_STAGE_A(As0, 0);
  SCHEDB();
  WAITV(4);
  GU_WRITEB(Bg0, Bu0);
  WAITL();

  // NT = 16 K-steps: 7 pairs (kt=0..13) + kt=14 + tail kt=15
  for (int k2 = 0; k2 < 7; ++k2) {
    const int kt = k2 * 2;
    GU_ITER(As0, Bg0, Bu0, As1, Bg1, Bu1, kt);
    GU_ITER(As1, Bg1, Bu1, As0, Bg0, Bu0, kt + 1);
  }
  GU_ITER(As0, Bg0, Bu0, As1, Bg1, Bu1, 14);
  WAITV(0);
  BARRIER();
  GU_COMPUTE(As1, Bg1, Bu1);

#undef GU_LOADB
#undef GU_STAGE_A
#undef GU_WRITEB
#undef GU_COMPUTE
#undef GU_ITER

  const int hbase = offs[e];
#pragma unroll
  for (int mi = 0; mi < 4; ++mi)
#pragma unroll
    for (int rr = 0; rr < 4; ++rr) {
      int grow = mt * GBM + wr + mi * 16 + lk * 4 + rr;   // C/D: row=(lane>>4)*4+reg
      if (grow < cnt) {
        size_t hrow = (size_t)(hbase + grow) * I_DIM;
#pragma unroll
        for (int ni = 0; ni < 2; ++ni) {
          int col = i0 + wc + ni * 16 + lr;               // C/D: col=lane&15
          h[hrow + col] = f2bf(gelu_fast(accg[mi][ni][rr]) * accu[mi][ni][rr]);
        }
      }
    }
}

// ===================== down GEMM: all-bf16, counted-vmcnt, split-K =====================
__global__ __launch_bounds__(256) void k_down6(
    const u16* __restrict__ h, const u16* __restrict__ w2b,
    const int* __restrict__ counts, const int* __restrict__ offs, const int* __restrict__ ids,
    const float* __restrict__ wts, float* __restrict__ out) {
  const int e = blockIdx.z;
  const int mt = blockIdx.x & 15, ks = blockIdx.x >> 4, nt = blockIdx.y;
  const int cnt = counts[e];
  if (mt * BM >= cnt) return;
  __shared__ u16 As0[BM * BK], As1[BM * BK];   // 16 KB each
  __shared__ u16 Bs0[BN * BK], Bs1[BN * BK];   // 8 KB each
  const int tid = threadIdx.x, lane = tid & 63, wid = tid >> 6;
  const int wr = (wid >> 1) * 64, wc = (wid & 1) * 32;
  const int lr = lane & 15, lk = lane >> 4;
  const int n0 = nt * BN;
  const int hbase = offs[e];
  const int lrow = lane >> 3;
  const int lgs = (lane & 7) ^ (lrow & 7);
  const int sw = lr & 7;

  const u16* asrc[4];
#pragma unroll
  for (int i = 0; i < 4; ++i) {
    int rg = mt * BM + wid * 32 + i * 8 + lrow;
    if (rg >= cnt) rg = cnt - 1;
    asrc[i] = h + (size_t)(hbase + rg) * I_DIM + lgs * 8;
  }
  const u16* bsrc[2];
#pragma unroll
  for (int i = 0; i < 2; ++i)
    bsrc[i] = w2b + (size_t)(e * H_DIM + n0 + wid * 16 + i * 8 + lrow) * I_DIM + lgs * 8;
  const int awofs = wid * 32 * BK;
  const int bwofs = wid * 16 * BK;

  f32x4 acc[4][2];
#pragma unroll
  for (int mi = 0; mi < 4; ++mi)
#pragma unroll
    for (int ni = 0; ni < 2; ++ni) acc[mi][ni] = (f32x4)0.f;

  const int KT = I_DIM / BK / KS;           // 32
  const int kbase = ks * KT * BK;

#define DN_STAGE(ASD, BSD, ko) do {                                         \
    _Pragma("unroll") for (int i = 0; i < 4; ++i)                           \
      gload_lds16(asrc[i] + (ko), (u16*)(ASD) + awofs + i * 8 * BK);        \
    _Pragma("unroll") for (int i = 0; i < 2; ++i)                           \
      gload_lds16(bsrc[i] + (ko), (u16*)(BSD) + bwofs + i * 8 * BK);        \
  } while (0)
#define DN_COMPUTE(AS, BS) do {                                             \
    _Pragma("unroll") for (int kk = 0; kk < 2; ++kk) {                      \
      const int colg = kk * 4 + lk;                                         \
      const int gsw = (colg ^ sw) << 3;                                     \
      bf16x8 a[4], b[2];                                                    \
      _Pragma("unroll") for (int mi = 0; mi < 4; ++mi)                      \
        a[mi] = *reinterpret_cast<const bf16x8*>((u16*)(AS) + (wr + mi * 16 + lr) * BK + gsw); \
      _Pragma("unroll") for (int ni = 0; ni < 2; ++ni)                      \
        b[ni] = *reinterpret_cast<const bf16x8*>((u16*)(BS) + (wc + ni * 16 + lr) * BK + gsw); \
      __builtin_amdgcn_s_setprio(1);                                        \
      _Pragma("unroll") for (int mi = 0; mi < 4; ++mi)                      \
        _Pragma("unroll") for (int ni = 0; ni < 2; ++ni)                    \
          acc[mi][ni] = __builtin_amdgcn_mfma_f32_16x16x32_bf16(a[mi], b[ni], acc[mi][ni], 0, 0, 0); \
      __builtin_amdgcn_s_setprio(0);                                        \
    }                                                                       \
  } while (0)
// ledger: enter with stage(kt)x6; issue stage(kt+1)x6 -> 12; vmcnt(6) drains stage(kt)
#define DN_ITER(ASC, BSC, ASN, BSN, kt) do {                                \
    DN_STAGE(ASN, BSN, kbase + ((kt) + 1) * BK);                            \
    SCHEDB();                                                               \
    WAITV(6);                                                               \
    BARRIER();                                                              \
    DN_COMPUTE(ASC, BSC);                                                   \
    BARRIER();                                                              \
  } while (0)

  DN_STAGE(As0, Bs0, kbase);
  SCHEDB();
  // KT = 32: 15 pairs (kt=0..29) + kt=30 + tail kt=31
  for (int k2 = 0; k2 < 15; ++k2) {
    const int kt = k2 * 2;
    DN_ITER(As0, Bs0, As1, Bs1, kt);
    DN_ITER(As1, Bs1, As0, Bs0, kt + 1);
  }
  DN_ITER(As0, Bs0, As1, Bs1, 30);
  WAITV(0);
  BARRIER();
  DN_COMPUTE(As1, Bs1);

#undef DN_STAGE
#undef DN_COMPUTE
#undef DN_ITER

#pragma unroll
  for (int mi = 0; mi < 4; ++mi)
#pragma unroll
    for (int rr = 0; rr < 4; ++rr) {
      int grow = mt * BM + wr + mi * 16 + lk * 4 + rr;
      if (grow < cnt) {
        int tok = ids[e * T_TOK + grow];
        float w = wts[e * T_TOK + grow];
#pragma unroll
        for (int ni = 0; ni < 2; ++ni) {
          int col = n0 + wc + ni * 16 + lr;
          atomicAdd(&out[(size_t)tok * H_DIM + col], w * acc[mi][ni][rr]);
        }
      }
    }
}

extern "C" void kernel_launch(void* const* d_in, const int* in_sizes, int n_in,
                              void* d_out, int out_size, void* d_ws, size_t ws_size,
                              hipStream_t stream) {
  const float* x   = (const float*)d_in[0];
  const float* gw  = (const float*)d_in[1];
  const float* w1g = (const float*)d_in[2];
  const float* w1u = (const float*)d_in[3];
  const float* w2  = (const float*)d_in[4];
  float* out = (float*)d_out;
  char* ws = (char*)d_ws;

  const size_t MB = 1u << 20;
  const size_t OFF_XB  = 0;                    // 4 MB
  const size_t OFF_H   = 4 * MB;               // 32 MB
  const size_t OFF_W2B = OFF_H + 32 * MB;      // 64 MB
  const size_t OFF_IDS = OFF_W2B + 64 * MB;
  const size_t OFF_WTS = OFF_IDS + (64u << 10);
  const size_t OFF_CNT = OFF_WTS + (64u << 10);

  u16* xb     = (u16*)(ws + OFF_XB);
  u16* h      = (u16*)(ws + OFF_H);
  u16* w2b    = (u16*)(ws + OFF_W2B);
  int* ids    = (int*)(ws + OFF_IDS);
  float* wts  = (float*)(ws + OFF_WTS);
  int* counts = (int*)(ws + OFF_CNT);
  int* offs   = counts + 8;

  k_prep<<<2048, 256, 0, stream>>>(x, out, xb, counts);
  k_router<<<512, 256, 0, stream>>>(x, gw, counts, ids, wts);
  k_offs<<<1, 64, 0, stream>>>(counts, offs);
  // x = mt (fastest: consecutive blocks share the same B tile), y = nt, z = expert / cvt
  k_gateup6<<<dim3(T_TOK / GBM, I_DIM / BN, E_NUM + 1), 512, 0, stream>>>(
      xb, w1g, w1u, w2, w2b, counts, offs, ids, h);
  k_down6<<<dim3((T_TOK / BM) * KS, H_DIM / BN, E_NUM), 256, 0, stream>>>(
      h, w2b, counts, offs, ids, wts, out);
}